// Round 1
// baseline (389.699 us; speedup 1.0000x reference)
//
#include <hip/hip_runtime.h>
#include <hip/hip_bf16.h>
#include <math.h>

#define B_TOT 16384
#define NBR   8
#define DV    256    // VOCAB
#define FF    1024   // FFN
#define ROWS  128    // rows per block
#define FC    64     // FFN chunk
#define NCHUNK (FF / FC)

using bf16x8 = __attribute__((ext_vector_type(8))) short;
using f32x4  = __attribute__((ext_vector_type(4))) float;

__device__ __forceinline__ unsigned short f2bf(float f) {
    unsigned int u = __builtin_bit_cast(unsigned int, f);
    unsigned int r = (u + 0x7fffu + ((u >> 16) & 1u)) >> 16;
    return (unsigned short)r;
}
__device__ __forceinline__ float bf2f(unsigned short h) {
    unsigned int u = ((unsigned int)h) << 16;
    return __builtin_bit_cast(float, u);
}
__device__ __forceinline__ float gelu_exact(float x) {
    return 0.5f * x * (1.0f + erff(x * 0.70710678118654752f));
}

// LDS regions (bytes):
//  Xs: [128 rows][256 k] bf16, swizzled   -> 65536
//  WB: shared weight chunk buffer          -> 32768  (Bt1 [64][256] or Bt2 [256][64] bf16)
//  Hs: [128 rows][64 k] bf16, swizzled     -> 16384
struct alignas(16) LdsBuf {
    char xs[65536];
    char wb[32768];
    char hs[16384];
};

__global__ __launch_bounds__(512, 2)
void belayer_fused(const float* __restrict__ x,  const float* __restrict__ U1,
                   const float* __restrict__ b1, const float* __restrict__ U2,
                   const float* __restrict__ b2, const float* __restrict__ lnw,
                   const float* __restrict__ lnb, float* __restrict__ out)
{
    __shared__ LdsBuf smem;
    char* Xs = smem.xs;
    char* WB = smem.wb;
    char* Hs = smem.hs;

    const int tid  = threadIdx.x;
    const int lane = tid & 63;
    const int wave = tid >> 6;          // 0..7
    const int bid  = blockIdx.x;
    const int n    = bid >> 7;          // branch 0..7
    const int tile = bid & 127;         // row tile within branch
    const int row0 = tile * ROWS;

    const float* U1n = U1 + (size_t)n * DV * FF;
    const float* U2n = U2 + (size_t)n * FF * DV;

    // ---- stage x tile -> Xs (bf16, swizzled). also the skip source. ----
    #pragma unroll
    for (int pass = 0; pass < 8; ++pass) {
        int r  = (tid >> 5) + pass * 16;        // 0..127
        int kc = (tid & 31) * 8;                // 0..248
        const float* src = x + ((size_t)(row0 + r) * NBR + n) * DV + kc;
        f32x4 v0 = *(const f32x4*)src;
        f32x4 v1 = *(const f32x4*)(src + 4);
        bf16x8 h;
        h[0] = (short)f2bf(v0[0]); h[1] = (short)f2bf(v0[1]);
        h[2] = (short)f2bf(v0[2]); h[3] = (short)f2bf(v0[3]);
        h[4] = (short)f2bf(v1[0]); h[5] = (short)f2bf(v1[1]);
        h[6] = (short)f2bf(v1[2]); h[7] = (short)f2bf(v1[3]);
        int off = ((r * 256 + kc) * 2) ^ ((r & 7) << 4);
        *(bf16x8*)(Xs + off) = h;
    }

    // persistent GEMM2 accumulators: wave owns rows [wave*16, wave*16+16), all 256 cols
    f32x4 acc2[16];
    #pragma unroll
    for (int j = 0; j < 16; ++j) acc2[j] = (f32x4){0.f, 0.f, 0.f, 0.f};

    const int Rw = (wave >> 2) * 64;        // GEMM1 wave row-block (2x4 tiling of 128x64)
    const int C0 = (wave & 3) * 16;         // GEMM1 wave col-block
    const int r0 = wave * 16;               // GEMM2 wave rows

    for (int fc = 0; fc < NCHUNK; ++fc) {
        __syncthreads();   // prev chunk's WB/Hs reads done; (first iter: Xs staged)

        // ---- stage Bt1 = U1[n][:, fc*64 .. +64] transposed -> WB [64 nn][256 kk] ----
        {
            int nn = tid & 63;
            int kgBase = tid >> 6;  // 0..7
            #pragma unroll
            for (int pass = 0; pass < 4; ++pass) {
                int kg = kgBase + pass * 8;   // 0..31 ; kk = kg*8..+8
                const float* src = U1n + (size_t)(kg * 8) * FF + fc * 64 + nn;
                bf16x8 hv;
                #pragma unroll
                for (int i = 0; i < 8; ++i)
                    hv[i] = (short)f2bf(src[(size_t)i * FF]);
                int off = ((nn * 256 + kg * 8) * 2) ^ ((nn & 7) << 4);
                *(bf16x8*)(WB + off) = hv;
            }
        }
        __syncthreads();

        // ---- GEMM1 chunk: (128x256) x (256x64) ; wave tile 64x16 ----
        f32x4 acc1[4];
        #pragma unroll
        for (int m = 0; m < 4; ++m) acc1[m] = (f32x4){0.f, 0.f, 0.f, 0.f};

        #pragma unroll
        for (int ks = 0; ks < 8; ++ks) {
            int kb = ks * 32 + (lane >> 4) * 8;
            int nn = C0 + (lane & 15);
            bf16x8 bfrag = *(const bf16x8*)(WB + (((nn * 256 + kb) * 2) ^ ((nn & 7) << 4)));
            #pragma unroll
            for (int mf = 0; mf < 4; ++mf) {
                int rr = Rw + mf * 16 + (lane & 15);
                bf16x8 afrag = *(const bf16x8*)(Xs + (((rr * 256 + kb) * 2) ^ ((rr & 7) << 4)));
                acc1[mf] = __builtin_amdgcn_mfma_f32_16x16x32_bf16(afrag, bfrag, acc1[mf], 0, 0, 0);
            }
        }

        // bias + exact gelu -> Hs (bf16, swizzled). D-layout: col=lane&15, row=(lane>>4)*4+r
        {
            float b1v = b1[n * FF + fc * 64 + C0 + (lane & 15)];
            int kk = C0 + (lane & 15);
            #pragma unroll
            for (int mf = 0; mf < 4; ++mf) {
                #pragma unroll
                for (int r = 0; r < 4; ++r) {
                    int row = Rw + mf * 16 + (lane >> 4) * 4 + r;
                    float g = gelu_exact(acc1[mf][r] + b1v);
                    int off = ((row * 64 + kk) * 2) ^ ((row & 7) << 4);
                    *(unsigned short*)(Hs + off) = f2bf(g);
                }
            }
        }
        __syncthreads();   // Hs complete; all Bt1 reads done -> WB reusable

        // ---- stage Bt2 = U2[n][fc*64..+64, :] transposed -> WB [256 nn][64 kk] ----
        {
            int nn = tid & 255;
            int kgBase = tid >> 8;   // 0..1
            #pragma unroll
            for (int pass = 0; pass < 4; ++pass) {
                int kg = kgBase + pass * 2;  // 0..7
                const float* src = U2n + (size_t)(fc * 64 + kg * 8) * DV + nn;
                bf16x8 hv;
                #pragma unroll
                for (int i = 0; i < 8; ++i)
                    hv[i] = (short)f2bf(src[(size_t)i * DV]);
                int off = ((nn * 64 + kg * 8) * 2) ^ ((nn & 7) << 4);
                *(bf16x8*)(WB + off) = hv;
            }
        }
        __syncthreads();

        // ---- GEMM2 chunk: (128x64) x (64x256) ; wave tile 16x256, accumulate ----
        #pragma unroll
        for (int ks = 0; ks < 2; ++ks) {
            int kb = ks * 32 + (lane >> 4) * 8;
            int rr = r0 + (lane & 15);
            bf16x8 afrag = *(const bf16x8*)(Hs + (((rr * 64 + kb) * 2) ^ ((rr & 7) << 4)));
            #pragma unroll
            for (int jf = 0; jf < 16; ++jf) {
                int nn = jf * 16 + (lane & 15);
                bf16x8 bfrag = *(const bf16x8*)(WB + (((nn * 64 + kb) * 2) ^ ((nn & 7) << 4)));
                acc2[jf] = __builtin_amdgcn_mfma_f32_16x16x32_bf16(afrag, bfrag, acc2[jf], 0, 0, 0);
            }
        }
    }

    // ---- epilogue: +b2, LayerNorm(256) per row, gelu, +skip, store fp32 ----
    float s[4]  = {0.f, 0.f, 0.f, 0.f};
    float sq[4] = {0.f, 0.f, 0.f, 0.f};
    #pragma unroll
    for (int jf = 0; jf < 16; ++jf) {
        float b2v = b2[n * DV + jf * 16 + (lane & 15)];
        #pragma unroll
        for (int r = 0; r < 4; ++r) {
            float v = acc2[jf][r] + b2v;
            acc2[jf][r] = v;
            s[r]  += v;
            sq[r] += v * v;
        }
    }
    #pragma unroll
    for (int m = 1; m < 16; m <<= 1) {
        #pragma unroll
        for (int r = 0; r < 4; ++r) {
            s[r]  += __shfl_xor(s[r],  m, 64);
            sq[r] += __shfl_xor(sq[r], m, 64);
        }
    }
    float mu[4], rs[4];
    #pragma unroll
    for (int r = 0; r < 4; ++r) {
        mu[r] = s[r] * (1.0f / 256.0f);
        float var = sq[r] * (1.0f / 256.0f) - mu[r] * mu[r];
        rs[r] = rsqrtf(var + 1e-5f);
    }
    #pragma unroll
    for (int jf = 0; jf < 16; ++jf) {
        int col = jf * 16 + (lane & 15);
        float lw = lnw[col];
        float lb = lnb[col];
        float b2dummy = 0.0f; (void)b2dummy;
        #pragma unroll
        for (int r = 0; r < 4; ++r) {
            int row = r0 + (lane >> 4) * 4 + r;
            float v = (acc2[jf][r] - mu[r]) * rs[r] * lw + lb;
            float g = gelu_exact(v);
            unsigned short sk = *(const unsigned short*)(Xs + (((row * 256 + col) * 2) ^ ((row & 7) << 4)));
            out[((size_t)(row0 + row) * NBR + n) * DV + col] = bf2f(sk) + g;
        }
    }
}

extern "C" void kernel_launch(void* const* d_in, const int* in_sizes, int n_in,
                              void* d_out, int out_size, void* d_ws, size_t ws_size,
                              hipStream_t stream) {
    const float* x   = (const float*)d_in[0];
    const float* U1  = (const float*)d_in[1];
    const float* b1  = (const float*)d_in[2];
    const float* U2  = (const float*)d_in[3];
    const float* b2  = (const float*)d_in[4];
    const float* lnw = (const float*)d_in[5];
    const float* lnb = (const float*)d_in[6];
    float* out = (float*)d_out;

    dim3 grid(NBR * (B_TOT / ROWS));   // 1024 blocks: bid = n*128 + tile
    dim3 block(512);
    belayer_fused<<<grid, block, 0, stream>>>(x, U1, b1, U2, b2, lnw, lnb, out);
}

// Round 2
// 270.299 us; speedup vs baseline: 1.4417x; 1.4417x over previous
//
#include <hip/hip_runtime.h>
#include <hip/hip_bf16.h>

#define B_TOT 16384
#define NBR   8
#define DV    256    // VOCAB
#define FF    1024   // FFN
#define ROWS  128    // rows per block
#define FC    64     // FFN chunk
#define NCHUNK 16

using bf16x8 = __attribute__((ext_vector_type(8))) short;
using f32x4  = __attribute__((ext_vector_type(4))) float;

__device__ __forceinline__ unsigned short f2bf(float f) {
    unsigned int u = __builtin_bit_cast(unsigned int, f);
    unsigned int r = (u + 0x7fffu + ((u >> 16) & 1u)) >> 16;
    return (unsigned short)r;
}
__device__ __forceinline__ float bf2f(unsigned short h) {
    unsigned int u = ((unsigned int)h) << 16;
    return __builtin_bit_cast(float, u);
}
// gelu(x) ~= x * sigmoid(1.595769122x + 0.0713548163x^3), in exp2 domain (~8 VALU)
__device__ __forceinline__ float gelu_fast(float x) {
    float x2 = x * x;
    float z  = x * fmaf(x2, -0.1029434959f, -2.3022078770f);
    float e  = __builtin_amdgcn_exp2f(z);
    return x * __builtin_amdgcn_rcpf(1.0f + e);
}

#define GLL(gsrc, ldst) __builtin_amdgcn_global_load_lds((const unsigned int*)(gsrc), (unsigned int*)(ldst), 16, 0, 0)

// ---------------- prep: fp32 weights -> bf16 swizzled LDS chunk images ----------------
// w1img: per (n,c) 32KB image of Bt1 [64 nn][256 kk]: val = U1[n][kk][c*64+nn]
// w2img: per (n,c) 32KB image of Bt2 [256 nn][64 kk]: val = U2[n][c*64+kk][nn]
__global__ void prep_weights(const float* __restrict__ U1, const float* __restrict__ U2,
                             unsigned short* __restrict__ w1img, unsigned short* __restrict__ w2img)
{
    const int b = blockIdx.x;          // 0..127
    const int n = b >> 4, c = b & 15;
    const int tid = threadIdx.x;       // 0..255
    char* img1 = (char*)(w1img) + ((size_t)b << 15);
    char* img2 = (char*)(w2img) + ((size_t)b << 15);
    const float* U1n = U1 + (size_t)n * DV * FF;
    const float* U2n = U2 + (size_t)n * FF * DV;
    #pragma unroll 4
    for (int e = 0; e < 64; ++e) {
        int kk = e * 4 + (tid >> 6);
        int nn = tid & 63;
        float v = U1n[(size_t)kk * FF + c * 64 + nn];
        unsigned off = ((unsigned)(nn * 256 + kk) * 2u) ^ (unsigned)((nn & 7) << 4);
        *(unsigned short*)(img1 + off) = f2bf(v);
    }
    #pragma unroll 4
    for (int e = 0; e < 64; ++e) {
        int nn = tid;  // 0..255
        float v = U2n[(size_t)(c * 64 + e) * DV + nn];
        unsigned off = ((unsigned)(nn * 64 + e) * 2u) ^ (unsigned)((nn & 7) << 4);
        *(unsigned short*)(img2 + off) = f2bf(v);
    }
}

// ---------------- main fused kernel ----------------
struct alignas(16) Lds {
    char xs[65536];   // [128][256] bf16, swz ^((row&7)<<4)
    char b1[32768];   // Bt1 [64 nn][256 kk] bf16 swz
    char b2[32768];   // Bt2 [256 nn][64 kk] bf16 swz
    char hs[16384];   // [128][64] bf16 swz ; epilogue: LN scratch f32[1024]
};

__global__ __launch_bounds__(512, 2)
void belayer_main(const float* __restrict__ x,
                  const unsigned short* __restrict__ w1img,
                  const unsigned short* __restrict__ w2img,
                  const float* __restrict__ b1, const float* __restrict__ b2,
                  const float* __restrict__ lnw, const float* __restrict__ lnb,
                  float* __restrict__ out)
{
    __shared__ Lds S;
    const int tid  = threadIdx.x;
    const int lane = tid & 63;
    const int wave = tid >> 6;          // 0..7
    const int n    = blockIdx.x & 7;    // branch == XCD affinity
    const int tile = blockIdx.x >> 3;
    const int row0 = tile * ROWS;

    // ---- stage x tile -> Xs (bf16, swz). one-time; also the skip source ----
    #pragma unroll
    for (int p = 0; p < 8; ++p) {
        int r  = (tid >> 5) + p * 16;       // 0..127
        int kc = (tid & 31) * 8;            // 0..248
        const float* src = x + ((size_t)(row0 + r) * NBR + n) * DV + kc;
        f32x4 v0 = *(const f32x4*)src;
        f32x4 v1 = *(const f32x4*)(src + 4);
        bf16x8 h;
        h[0] = (short)f2bf(v0[0]); h[1] = (short)f2bf(v0[1]);
        h[2] = (short)f2bf(v0[2]); h[3] = (short)f2bf(v0[3]);
        h[4] = (short)f2bf(v1[0]); h[5] = (short)f2bf(v1[1]);
        h[6] = (short)f2bf(v1[2]); h[7] = (short)f2bf(v1[3]);
        *(bf16x8*)(S.xs + (((r * 256 + kc) * 2) ^ ((r & 7) << 4))) = h;
    }
    // ---- issue Bt1[0] DMA ----
    {
        const char* g = (const char*)w1img + ((size_t)(n * 16) << 15) + (wave << 12) + lane * 16;
        char* l = S.b1 + (wave << 12);
        #pragma unroll
        for (int i = 0; i < 4; ++i) GLL(g + (i << 10), l + (i << 10));
    }
    __syncthreads();   // Xs visible; Bt1[0] drained+published

    // ---- GEMM1 A in registers: wave pair shares 32 rows; 16 frags = 64 VGPR ----
    const int rowgrp = wave >> 1;          // 0..3 -> rows rowgrp*32..+32
    const int colsel = wave & 1;           // 0..1 -> H cols colsel*32..+32
    bf16x8 A[2][8];
    #pragma unroll
    for (int rf = 0; rf < 2; ++rf)
        #pragma unroll
        for (int ks = 0; ks < 8; ++ks) {
            int rr = rowgrp * 32 + rf * 16 + (lane & 15);
            int kk = ks * 32 + (lane >> 4) * 8;
            A[rf][ks] = *(const bf16x8*)(S.xs + (((rr * 256 + kk) * 2) ^ ((rr & 7) << 4)));
        }

    // GEMM2: wave tile 64x64: rows rowg2*64, cols colg2*64
    const int rowg2 = wave >> 2;           // 0..1
    const int colg2 = wave & 3;            // 0..3
    f32x4 acc2[4][4];
    #pragma unroll
    for (int i = 0; i < 4; ++i)
        #pragma unroll
        for (int j = 0; j < 4; ++j) acc2[i][j] = (f32x4){0.f, 0.f, 0.f, 0.f};

    for (int c = 0; c < NCHUNK; ++c) {
        // issue Bt2[c] DMA (flight hidden under GEMM1)
        {
            const char* g = (const char*)w2img + ((size_t)(n * 16 + c) << 15) + (wave << 12) + lane * 16;
            char* l = S.b2 + (wave << 12);
            #pragma unroll
            for (int i = 0; i < 4; ++i) GLL(g + (i << 10), l + (i << 10));
        }
        // ---- GEMM1: out 32x32 per wave, A in regs, B from Bt1 ----
        f32x4 acc1[2][2];
        #pragma unroll
        for (int i = 0; i < 2; ++i)
            #pragma unroll
            for (int j = 0; j < 2; ++j) acc1[i][j] = (f32x4){0.f, 0.f, 0.f, 0.f};
        #pragma unroll
        for (int ks = 0; ks < 8; ++ks) {
            int kk = ks * 32 + (lane >> 4) * 8;
            int nn0 = colsel * 32 + (lane & 15);
            int nn1 = nn0 + 16;
            bf16x8 bf0 = *(const bf16x8*)(S.b1 + (((nn0 * 256 + kk) * 2) ^ ((nn0 & 7) << 4)));
            bf16x8 bf1 = *(const bf16x8*)(S.b1 + (((nn1 * 256 + kk) * 2) ^ ((nn1 & 7) << 4)));
            acc1[0][0] = __builtin_amdgcn_mfma_f32_16x16x32_bf16(A[0][ks], bf0, acc1[0][0], 0, 0, 0);
            acc1[0][1] = __builtin_amdgcn_mfma_f32_16x16x32_bf16(A[0][ks], bf1, acc1[0][1], 0, 0, 0);
            acc1[1][0] = __builtin_amdgcn_mfma_f32_16x16x32_bf16(A[1][ks], bf0, acc1[1][0], 0, 0, 0);
            acc1[1][1] = __builtin_amdgcn_mfma_f32_16x16x32_bf16(A[1][ks], bf1, acc1[1][1], 0, 0, 0);
        }
        // ---- bias + gelu -> Hs ----
        #pragma unroll
        for (int cf = 0; cf < 2; ++cf) {
            int hk = colsel * 32 + cf * 16 + (lane & 15);
            float b1v = b1[n * FF + c * 64 + hk];
            #pragma unroll
            for (int rf = 0; rf < 2; ++rf)
                #pragma unroll
                for (int r = 0; r < 4; ++r) {
                    int row = rowgrp * 32 + rf * 16 + (lane >> 4) * 4 + r;
                    float g = gelu_fast(acc1[rf][cf][r] + b1v);
                    *(unsigned short*)(S.hs + (((row * 64 + hk) * 2) ^ ((row & 7) << 4))) = f2bf(g);
                }
        }
        __syncthreads();   // drains Bt2[c] DMA (covered by G1); publishes Hs + Bt2[c]; Bt1[c] readers done

        // issue Bt1[c+1] DMA (flight hidden under GEMM2)
        if (c < NCHUNK - 1) {
            const char* g = (const char*)w1img + ((size_t)(n * 16 + c + 1) << 15) + (wave << 12) + lane * 16;
            char* l = S.b1 + (wave << 12);
            #pragma unroll
            for (int i = 0; i < 4; ++i) GLL(g + (i << 10), l + (i << 10));
        }
        // ---- GEMM2: out 64x64 per wave, A from Hs, B from Bt2; accumulate ----
        #pragma unroll
        for (int ks = 0; ks < 2; ++ks) {
            int kb = ks * 32 + (lane >> 4) * 8;
            bf16x8 af[4], bfr[4];
            #pragma unroll
            for (int rf = 0; rf < 4; ++rf) {
                int rr = rowg2 * 64 + rf * 16 + (lane & 15);
                af[rf] = *(const bf16x8*)(S.hs + (((rr * 64 + kb) * 2) ^ ((rr & 7) << 4)));
            }
            #pragma unroll
            for (int cf = 0; cf < 4; ++cf) {
                int nn = colg2 * 64 + cf * 16 + (lane & 15);
                bfr[cf] = *(const bf16x8*)(S.b2 + (((nn * 64 + kb) * 2) ^ ((nn & 7) << 4)));
            }
            #pragma unroll
            for (int rf = 0; rf < 4; ++rf)
                #pragma unroll
                for (int cf = 0; cf < 4; ++cf)
                    acc2[rf][cf] = __builtin_amdgcn_mfma_f32_16x16x32_bf16(af[rf], bfr[cf], acc2[rf][cf], 0, 0, 0);
        }
        __syncthreads();   // drains Bt1[c+1] (covered by G2); publishes Bt1[c+1]; Hs/Bt2 readers done
    }

    // ---- epilogue: +b2, cross-wave LN(256), gelu, +skip, store ----
    float b2v[4];
    #pragma unroll
    for (int cf = 0; cf < 4; ++cf) b2v[cf] = b2[n * DV + colg2 * 64 + cf * 16 + (lane & 15)];

    float sA[4][4], sQ[4][4];
    #pragma unroll
    for (int rf = 0; rf < 4; ++rf)
        #pragma unroll
        for (int r = 0; r < 4; ++r) { sA[rf][r] = 0.f; sQ[rf][r] = 0.f; }
    #pragma unroll
    for (int rf = 0; rf < 4; ++rf)
        #pragma unroll
        for (int cf = 0; cf < 4; ++cf)
            #pragma unroll
            for (int r = 0; r < 4; ++r) {
                float v = acc2[rf][cf][r] + b2v[cf];
                acc2[rf][cf][r] = v;
                sA[rf][r] += v;
                sQ[rf][r] += v * v;
            }
    #pragma unroll
    for (int m = 1; m < 16; m <<= 1)
        #pragma unroll
        for (int rf = 0; rf < 4; ++rf)
            #pragma unroll
            for (int r = 0; r < 4; ++r) {
                sA[rf][r] += __shfl_xor(sA[rf][r], m, 64);
                sQ[rf][r] += __shfl_xor(sQ[rf][r], m, 64);
            }
    // partials -> LDS (reuse Hs): [s|sq][colg2][row 0..127]
    float* Lred = (float*)S.hs;
    if ((lane & 15) == 0) {
        #pragma unroll
        for (int rf = 0; rf < 4; ++rf)
            #pragma unroll
            for (int r = 0; r < 4; ++r) {
                int row = rowg2 * 64 + rf * 16 + (lane >> 4) * 4 + r;
                Lred[colg2 * 128 + row]       = sA[rf][r];
                Lred[512 + colg2 * 128 + row] = sQ[rf][r];
            }
    }
    __syncthreads();
    float mu[4][4], rs[4][4];
    #pragma unroll
    for (int rf = 0; rf < 4; ++rf)
        #pragma unroll
        for (int r = 0; r < 4; ++r) {
            int row = rowg2 * 64 + rf * 16 + (lane >> 4) * 4 + r;
            float ssum = Lred[row] + Lred[128 + row] + Lred[256 + row] + Lred[384 + row];
            float qsum = Lred[512 + row] + Lred[640 + row] + Lred[768 + row] + Lred[896 + row];
            float m_ = ssum * (1.0f / 256.0f);
            float var = qsum * (1.0f / 256.0f) - m_ * m_;
            mu[rf][r] = m_;
            rs[rf][r] = rsqrtf(var + 1e-5f);
        }
    #pragma unroll
    for (int cf = 0; cf < 4; ++cf) {
        int col = colg2 * 64 + cf * 16 + (lane & 15);
        float lw = lnw[col];
        float lb = lnb[col];
        #pragma unroll
        for (int rf = 0; rf < 4; ++rf)
            #pragma unroll
            for (int r = 0; r < 4; ++r) {
                int row = rowg2 * 64 + rf * 16 + (lane >> 4) * 4 + r;
                float v = (acc2[rf][cf][r] - mu[rf][r]) * rs[rf][r] * lw + lb;
                float g = gelu_fast(v);
                unsigned short sk = *(const unsigned short*)(S.xs + (((row * 256 + col) * 2) ^ ((row & 7) << 4)));
                out[((size_t)(row0 + row) * NBR + n) * DV + col] = bf2f(sk) + g;
            }
    }
}

extern "C" void kernel_launch(void* const* d_in, const int* in_sizes, int n_in,
                              void* d_out, int out_size, void* d_ws, size_t ws_size,
                              hipStream_t stream) {
    const float* x   = (const float*)d_in[0];
    const float* U1  = (const float*)d_in[1];
    const float* b1  = (const float*)d_in[2];
    const float* U2  = (const float*)d_in[3];
    const float* b2  = (const float*)d_in[4];
    const float* lnw = (const float*)d_in[5];
    const float* lnb = (const float*)d_in[6];
    float* out = (float*)d_out;

    unsigned short* w1img = (unsigned short*)d_ws;               // 4 MB
    unsigned short* w2img = w1img + (size_t)4 * 1024 * 1024 / 2; // 4 MB

    prep_weights<<<dim3(128), dim3(256), 0, stream>>>(U1, U2, w1img, w2img);
    belayer_main<<<dim3(1024), dim3(512), 0, stream>>>(x, w1img, w2img, b1, b2, lnw, lnb, out);
}